// Round 1
// baseline (1608.233 us; speedup 1.0000x reference)
//
#include <hip/hip_runtime.h>
#include <math.h>

#define EPSF 1e-9f
#define INV_SQRT128 0.08838834764831845f

// ---------------- cross-ratio of x rows 0..3 (128 dims) ----------------
__global__ void k_cr_init(const float* __restrict__ x, double* __restrict__ crinit) {
    int l = threadIdx.x; // 64 threads
    const int pa[4] = {0, 1, 0, 1};
    const int pb[4] = {2, 3, 3, 2};
    double inner[4];
    for (int p = 0; p < 4; p++) {
        const float* a = x + pa[p] * 128;
        const float* b = x + pb[p] * 128;
        double s = (double)a[l] * (double)b[l];
        double t = (double)a[l + 64] * (double)b[l + 64];
        s += (l == 63) ? -t : t;  // index 127 is the time coord
        for (int off = 32; off; off >>= 1) s += __shfl_xor(s, off);
        inner[p] = s;
    }
    if (l == 0) {
        double num = inner[0] * inner[1];
        double den = inner[2] * inner[3];
        if (fabs(den) < 1e-9) den = 1e-9;
        crinit[0] = num / den;
    }
}

// ---------------- normalize x rows (127 spatial + 1 time) ----------------
__global__ void k_normx(const float* __restrict__ x, float* __restrict__ xp, int N) {
    int wid = (blockIdx.x * blockDim.x + threadIdx.x) >> 6;
    int l = threadIdx.x & 63;
    if (wid >= N) return;
    const float* r = x + (size_t)wid * 128;
    float a = r[l];
    float b = r[l + 64];
    float pp = a * a + ((l < 63) ? b * b : 0.f);
    for (int off = 32; off; off >>= 1) pp += __shfl_xor(pp, off);
    float nm = fmaxf(sqrtf(pp), EPSF);
    float* o = xp + (size_t)wid * 128;
    o[l] = a / nm;
    o[l + 64] = (l == 63) ? b : b / nm;
}

// ---------------- q/k/v projection + head-normalize ----------------
// block = 384 threads = 6 waves: wave 0,1 -> q heads; 2,3 -> k heads; 4,5 -> v heads.
// Each lane owns one output column; its weight row (128 floats) lives in VGPRs.
// Node-row reads are wave-uniform -> scalar loads.
__global__ void __launch_bounds__(384, 2)
k_qkv(const float* __restrict__ xp,
      const float* __restrict__ Wq, const float* __restrict__ bq,
      const float* __restrict__ Wk, const float* __restrict__ bk,
      const float* __restrict__ Wv, const float* __restrict__ bv,
      float* __restrict__ qn, float* __restrict__ kn, float* __restrict__ vb,
      int N) {
    int w = threadIdx.x >> 6;   // 0..5
    int lane = threadIdx.x & 63;
    int half = w & 1;           // head
    int kind = w >> 1;          // 0=q,1=k,2=v
    const float* W = (kind == 0) ? Wq : ((kind == 1) ? Wk : Wv);
    const float* bias = (kind == 0) ? bq : ((kind == 1) ? bk : bv);
    float* outp = (kind == 0) ? qn : ((kind == 1) ? kn : vb);
    int orow = half * 64 + lane;

    float wreg[128];
    const float4* wp = (const float4*)(W + (size_t)orow * 128);
#pragma unroll
    for (int j = 0; j < 32; j++) {
        float4 t = wp[j];
        wreg[4 * j + 0] = t.x; wreg[4 * j + 1] = t.y;
        wreg[4 * j + 2] = t.z; wreg[4 * j + 3] = t.w;
    }
    float br = bias[orow];

    for (int n = blockIdx.x; n < N; n += gridDim.x) {
        const float* xr = xp + (size_t)n * 128;
        float acc = 0.f;
#pragma unroll
        for (int j = 0; j < 128; j++) acc = fmaf(xr[j], wreg[j], acc);
        acc += br;
        float val = acc;
        if (kind < 2) {
            float pp = (lane < 63) ? acc * acc : 0.f;
            for (int off = 32; off; off >>= 1) pp += __shfl_xor(pp, off);
            float nm = fmaxf(sqrtf(pp), EPSF);
            val = (lane < 63) ? (acc / nm) : acc;   // keep homogeneous coord
            if (kind == 0) {
                if (lane == 63) val = -val;          // fold uhg minus into q
                val *= INV_SQRT128;                  // fold 1/sqrt(IN_F) into q
            }
        }
        outp[(size_t)n * 128 + orow] = val;
    }
}

// ---------------- per-edge scores ----------------
// 32 lanes per edge: lanes 0-15 head0, 16-31 head1 (4 floats each).
__global__ void k_scores(const float* __restrict__ qn, const float* __restrict__ kn,
                         const int* __restrict__ ei, float* __restrict__ scores, int E) {
    int g = threadIdx.x >> 5;   // group in block (8)
    int l = threadIdx.x & 31;
    int head = l >> 4;
    int nGroups = (blockDim.x >> 5) * gridDim.x;
    for (int e = blockIdx.x * 8 + g; e < E; e += nGroups) {
        int r = ei[e];
        int c = ei[E + e];
        float4 q4 = ((const float4*)qn)[(size_t)r * 32 + l];
        float4 k4 = ((const float4*)kn)[(size_t)c * 32 + l];
        float p = q4.x * k4.x;
        p = fmaf(q4.y, k4.y, p);
        p = fmaf(q4.z, k4.z, p);
        p = fmaf(q4.w, k4.w, p);
        p += __shfl_xor(p, 1);
        p += __shfl_xor(p, 2);
        p += __shfl_xor(p, 4);
        p += __shfl_xor(p, 8);
        if ((l & 15) == 0) scores[(size_t)e * 2 + head] = p;
    }
}

// ---------------- global max over edges (per head) ----------------
__global__ void k_max(const float* __restrict__ scores, float* __restrict__ pmax, int E) {
    float m0 = -INFINITY, m1 = -INFINITY;
    int stride = blockDim.x * gridDim.x;
    for (int i = blockIdx.x * blockDim.x + threadIdx.x; i < E; i += stride) {
        float2 s = ((const float2*)scores)[i];
        m0 = fmaxf(m0, s.x);
        m1 = fmaxf(m1, s.y);
    }
    for (int off = 32; off; off >>= 1) {
        m0 = fmaxf(m0, __shfl_xor(m0, off));
        m1 = fmaxf(m1, __shfl_xor(m1, off));
    }
    __shared__ float sm[2][4];
    int w = threadIdx.x >> 6;
    if ((threadIdx.x & 63) == 0) { sm[0][w] = m0; sm[1][w] = m1; }
    __syncthreads();
    if (threadIdx.x == 0) {
        for (int i = 1; i < 4; i++) { m0 = fmaxf(m0, sm[0][i]); m1 = fmaxf(m1, sm[1][i]); }
        pmax[blockIdx.x * 2 + 0] = m0;
        pmax[blockIdx.x * 2 + 1] = m1;
    }
}

__global__ void k_max2(const float* __restrict__ pmax, float* __restrict__ mhead, int P) {
    float m0 = -INFINITY, m1 = -INFINITY;
    for (int i = threadIdx.x; i < P; i += blockDim.x) {
        m0 = fmaxf(m0, pmax[2 * i]);
        m1 = fmaxf(m1, pmax[2 * i + 1]);
    }
    for (int off = 32; off; off >>= 1) {
        m0 = fmaxf(m0, __shfl_xor(m0, off));
        m1 = fmaxf(m1, __shfl_xor(m1, off));
    }
    __shared__ float sm[2][4];
    int w = threadIdx.x >> 6;
    if ((threadIdx.x & 63) == 0) { sm[0][w] = m0; sm[1][w] = m1; }
    __syncthreads();
    if (threadIdx.x == 0) {
        for (int i = 1; i < 4; i++) { m0 = fmaxf(m0, sm[0][i]); m1 = fmaxf(m1, sm[1][i]); }
        mhead[0] = m0;
        mhead[1] = m1;
    }
}

// ---------------- global sum of exp (double accumulation) ----------------
__global__ void k_expsum(const float* __restrict__ scores, const float* __restrict__ mhead,
                         double* __restrict__ psum, int E) {
    double s0 = 0.0, s1 = 0.0;
    float m0 = mhead[0], m1 = mhead[1];
    int stride = blockDim.x * gridDim.x;
    for (int i = blockIdx.x * blockDim.x + threadIdx.x; i < E; i += stride) {
        float2 s = ((const float2*)scores)[i];
        s0 += exp((double)(s.x - m0));
        s1 += exp((double)(s.y - m1));
    }
    for (int off = 32; off; off >>= 1) {
        s0 += __shfl_xor(s0, off);
        s1 += __shfl_xor(s1, off);
    }
    __shared__ double sd[2][4];
    int w = threadIdx.x >> 6;
    if ((threadIdx.x & 63) == 0) { sd[0][w] = s0; sd[1][w] = s1; }
    __syncthreads();
    if (threadIdx.x == 0) {
        for (int i = 1; i < 4; i++) { s0 += sd[0][i]; s1 += sd[1][i]; }
        psum[blockIdx.x * 2 + 0] = s0;
        psum[blockIdx.x * 2 + 1] = s1;
    }
}

__global__ void k_sum2(const double* __restrict__ psum, float* __restrict__ sumf, int P) {
    double s0 = 0.0, s1 = 0.0;
    for (int i = threadIdx.x; i < P; i += blockDim.x) {
        s0 += psum[2 * i];
        s1 += psum[2 * i + 1];
    }
    for (int off = 32; off; off >>= 1) {
        s0 += __shfl_xor(s0, off);
        s1 += __shfl_xor(s1, off);
    }
    __shared__ double sd[2][4];
    int w = threadIdx.x >> 6;
    if ((threadIdx.x & 63) == 0) { sd[0][w] = s0; sd[1][w] = s1; }
    __syncthreads();
    if (threadIdx.x == 0) {
        for (int i = 1; i < 4; i++) { s0 += sd[0][i]; s1 += sd[1][i]; }
        sumf[0] = (float)s0;
        sumf[1] = (float)s1;
    }
}

// ---------------- CSR build ----------------
__global__ void k_hist(const int* __restrict__ ei, int* __restrict__ counts, int E) {
    int stride = blockDim.x * gridDim.x;
    for (int e = blockIdx.x * blockDim.x + threadIdx.x; e < E; e += stride)
        atomicAdd(&counts[ei[e]], 1);
}

__global__ void k_scan1(const int* __restrict__ counts, int* __restrict__ offs,
                        int* __restrict__ tsum, int N) {
    __shared__ int sd[256];
    int tile = blockIdx.x;
    int t = threadIdx.x;
    int i0 = tile * 1024 + t * 4;
    int v[4];
    int lsum = 0;
    for (int j = 0; j < 4; j++) {
        int idx = i0 + j;
        v[j] = (idx < N) ? counts[idx] : 0;
        lsum += v[j];
    }
    sd[t] = lsum;
    __syncthreads();
    for (int off = 1; off < 256; off <<= 1) {
        int val = sd[t];
        int add = (t >= off) ? sd[t - off] : 0;
        __syncthreads();
        sd[t] = val + add;
        __syncthreads();
    }
    int excl = (t == 0) ? 0 : sd[t - 1];
    if (t == 255) tsum[tile] = sd[255];
    int run = excl;
    for (int j = 0; j < 4; j++) {
        int idx = i0 + j;
        if (idx < N) offs[idx] = run;
        run += v[j];
    }
}

__global__ void k_scan2(int* __restrict__ tsum, int* __restrict__ offs, int T, int N) {
    if (threadIdx.x == 0) {
        int run = 0;
        for (int i = 0; i < T; i++) {
            int t = tsum[i];
            tsum[i] = run;
            run += t;
        }
        offs[N] = run;
    }
}

__global__ void k_scan3(int* __restrict__ offs, int* __restrict__ cursor,
                        const int* __restrict__ tsum, int N) {
    int i = blockIdx.x * blockDim.x + threadIdx.x;
    if (i < N) {
        int o = offs[i] + tsum[i >> 10];
        offs[i] = o;
        cursor[i] = o;
    }
}

__global__ void k_fill(const int* __restrict__ ei, int* __restrict__ cursor,
                       int* __restrict__ elist, int E) {
    int stride = blockDim.x * gridDim.x;
    for (int e = blockIdx.x * blockDim.x + threadIdx.x; e < E; e += stride) {
        int r = ei[e];
        int p = atomicAdd(&cursor[r], 1);
        elist[p] = e;
    }
}

// ---------------- aggregation: out_pre[n] = sum_e alpha*v[col] ----------------
__global__ void k_agg(const float* __restrict__ vb, const float* __restrict__ scores,
                      const int* __restrict__ ei, const int* __restrict__ offs,
                      const int* __restrict__ elist, const float* __restrict__ mhead,
                      const float* __restrict__ sumf, float* __restrict__ outp,
                      int N, int E) {
    int n = blockIdx.x * 8 + (threadIdx.x >> 5);
    if (n >= N) return;
    int l = threadIdx.x & 31;
    int head = l >> 4;
    float m = mhead[head];
    float sf = sumf[head];
    int s0 = offs[n], s1 = offs[n + 1];
    float4 acc = {0.f, 0.f, 0.f, 0.f};
    for (int i = s0; i < s1; i++) {
        int e = elist[i];
        int c = ei[E + e];
        float sc = scores[(size_t)e * 2 + head];
        float a = expf(sc - m) / sf;
        float4 v4 = ((const float4*)vb)[(size_t)c * 32 + l];
        acc.x = fmaf(v4.x, a, acc.x);
        acc.y = fmaf(v4.y, a, acc.y);
        acc.z = fmaf(v4.z, a, acc.z);
        acc.w = fmaf(v4.w, a, acc.w);
    }
    ((float4*)outp)[(size_t)n * 32 + l] = acc;
}

// ---------------- final GEMM: out = out_pre @ Wo.T + bo ----------------
__global__ void __launch_bounds__(256, 2)
k_out(const float* __restrict__ op, const float* __restrict__ Wo,
      const float* __restrict__ bo, float* __restrict__ out, int N) {
    int gw = (blockIdx.x * blockDim.x + threadIdx.x) >> 6;
    int nw = (gridDim.x * blockDim.x) >> 6;
    int o = threadIdx.x & 63;
    float wreg[128];
    const float4* wp = (const float4*)(Wo + (size_t)o * 128);
#pragma unroll
    for (int j = 0; j < 32; j++) {
        float4 t = wp[j];
        wreg[4 * j + 0] = t.x; wreg[4 * j + 1] = t.y;
        wreg[4 * j + 2] = t.z; wreg[4 * j + 3] = t.w;
    }
    float br = bo[o];
    for (int n = gw; n < N; n += nw) {
        const float* r = op + (size_t)n * 128;
        float acc = 0.f;
#pragma unroll
        for (int j = 0; j < 128; j++) acc = fmaf(r[j], wreg[j], acc);
        out[(size_t)n * 64 + o] = acc + br;
    }
}

// ---------------- cross-ratio restore ----------------
__global__ void k_crout(const float* __restrict__ out, const double* __restrict__ crinit,
                        float* __restrict__ scalef) {
    int l = threadIdx.x; // 64
    const int pa[4] = {0, 1, 0, 1};
    const int pb[4] = {2, 3, 3, 2};
    double inner[4];
    for (int p = 0; p < 4; p++) {
        const float* a = out + pa[p] * 64;
        const float* b = out + pb[p] * 64;
        double t = (double)a[l] * (double)b[l];
        if (l == 63) t = -t;
        for (int off = 32; off; off >>= 1) t += __shfl_xor(t, off);
        inner[p] = t;
    }
    if (l == 0) {
        double num = inner[0] * inner[1];
        double den = inner[2] * inner[3];
        if (fabs(den) < 1e-9) den = 1e-9;
        double crc = num / den;
        if (fabs(crc) < 1e-9) crc = 1e-9;
        double ratio = crinit[0] / crc;
        scalef[0] = (float)pow(fabs(ratio), 0.25);
    }
}

__global__ void k_scale(float* __restrict__ out, const float* __restrict__ scalef, int total4) {
    int i = blockIdx.x * blockDim.x + threadIdx.x;
    if (i >= total4) return;
    float s = scalef[0];
    float4 t = ((float4*)out)[i];
    t.x *= s; t.y *= s; t.z *= s; t.w *= s;
    ((float4*)out)[i] = t;
}

extern "C" void kernel_launch(void* const* d_in, const int* in_sizes, int n_in,
                              void* d_out, int out_size, void* d_ws, size_t ws_size,
                              hipStream_t stream) {
    const float* x  = (const float*)d_in[0];
    const int*   ei = (const int*)d_in[1];
    const float* Wq = (const float*)d_in[2];
    const float* bq = (const float*)d_in[3];
    const float* Wk = (const float*)d_in[4];
    const float* bk = (const float*)d_in[5];
    const float* Wv = (const float*)d_in[6];
    const float* bv = (const float*)d_in[7];
    const float* Wo = (const float*)d_in[8];
    const float* bo = (const float*)d_in[9];
    float* out = (float*)d_out;

    const int N = in_sizes[0] / 128;
    const int E = in_sizes[1] / 2;
    const size_t NR = (size_t)N * 128;

    float* qn = (float*)d_ws;       // N*128 ; later reused as out_pre
    float* kn = qn + NR;            // N*128
    float* vb = kn + NR;            // N*128
    float* xp = vb + NR;            // N*128 ; region reused after k_qkv:
    float* scores = xp;             //   E*2 floats
    int* counts = (int*)(scores + (size_t)E * 2);
    int* offs   = counts + N;       // N+1
    int* cursor = offs + N + 1;     // N
    int* elist  = cursor + N;       // E
    int* tsum   = elist + E;        // tiles

    double* crinit = (double*)(xp + NR);
    double* psum   = crinit + 1;            // 1024 doubles
    float* pmax    = (float*)(psum + 1024); // 1024 floats
    float* mhead   = pmax + 1024;           // 2
    float* sumf    = mhead + 2;             // 2
    float* scalef  = sumf + 2;              // 1

    float* out_pre = qn;  // reuse

    const int T = (N + 1023) / 1024;

    k_cr_init<<<1, 64, 0, stream>>>(x, crinit);
    k_normx<<<(N * 64 + 255) / 256, 256, 0, stream>>>(x, xp, N);
    k_qkv<<<512, 384, 0, stream>>>(xp, Wq, bq, Wk, bk, Wv, bv, qn, kn, vb, N);
    k_scores<<<2048, 256, 0, stream>>>(qn, kn, ei, scores, E);
    k_max<<<512, 256, 0, stream>>>(scores, pmax, E);
    k_max2<<<1, 256, 0, stream>>>(pmax, mhead, 512);
    k_expsum<<<512, 256, 0, stream>>>(scores, mhead, psum, E);
    k_sum2<<<1, 256, 0, stream>>>(psum, sumf, 512);
    hipMemsetAsync(counts, 0, (size_t)N * sizeof(int), stream);
    k_hist<<<1024, 256, 0, stream>>>(ei, counts, E);
    k_scan1<<<T, 256, 0, stream>>>(counts, offs, tsum, N);
    k_scan2<<<1, 64, 0, stream>>>(tsum, offs, T, N);
    k_scan3<<<(N + 255) / 256, 256, 0, stream>>>(offs, cursor, tsum, N);
    k_fill<<<1024, 256, 0, stream>>>(ei, cursor, elist, E);
    k_agg<<<(N + 7) / 8, 256, 0, stream>>>(vb, scores, ei, offs, elist, mhead, sumf, out_pre, N, E);
    k_out<<<512, 256, 0, stream>>>(out_pre, Wo, bo, out, N);
    k_crout<<<1, 64, 0, stream>>>(out, crinit, scalef);
    k_scale<<<(N * 16 + 255) / 256, 256, 0, stream>>>(out, scalef, N * 16);
}